// Round 8
// baseline (158.540 us; speedup 1.0000x reference)
//
#include <hip/hip_runtime.h>
#include <float.h>
#include <stdint.h>

// Problem constants
#define BATCHES 32
#define P 1024
#define KNN 16
#define C 64
#define H 128
#define N (BATCHES * P)   // 32768
#define NCOLS 384         // U(128) | V(128) | S(128)
#define SPLITS 16
#define CPS 64            // candidates per split (P / SPLITS)
#define PADH 132          // LDS row pad for gemm staging

typedef short short8 __attribute__((ext_vector_type(8)));
typedef float floatx4 __attribute__((ext_vector_type(4)));

__device__ __forceinline__ unsigned short f2bf(float f) {
    unsigned u = __float_as_uint(f);
    unsigned r = (u + 0x7FFF + ((u >> 16) & 1)) >> 16;   // RNE
    return (unsigned short)r;
}

struct alignas(16) F4 { float x, y, z, w; };

// ---------------------------------------------------------------------------
// prep: blocks 0..95   -> WcatT (bf16 [384][64]) + bias_cat (fp32 [384])
//       blocks 96..223 -> posq[N] = (x, y, z, x²+y²+z²)
// ---------------------------------------------------------------------------
__global__ __launch_bounds__(256) void prep_kernel(
    const float* __restrict__ W_e, const float* __restrict__ b_e,
    const float* __restrict__ W_sc, const float* __restrict__ b_sc,
    const float* __restrict__ pos,
    unsigned short* __restrict__ WT, float* __restrict__ bias,
    F4* __restrict__ posq)
{
    int b = blockIdx.x;
    if (b < 96) {
        int i = b * 256 + threadIdx.x;           // 0 .. 384*64-1
        int col = i >> 6, c = i & 63;
        float w;
        if (col < 128)      w = W_e[c * 128 + col] - W_e[(64 + c) * 128 + col];
        else if (col < 256) w = W_e[(64 + c) * 128 + (col - 128)];
        else                w = W_sc[c * 128 + (col - 256)];
        WT[col * 64 + c] = f2bf(w);
        if (c == 0)
            bias[col] = (col < 128) ? b_e[col] : (col < 256 ? 0.0f : b_sc[col - 256]);
    } else {
        int i = (b - 96) * 256 + threadIdx.x;    // 0 .. N-1
        float x = pos[i * 3 + 0], y = pos[i * 3 + 1], z = pos[i * 3 + 2];
        float sq = __fadd_rn(__fadd_rn(__fmul_rn(x, x), __fmul_rn(y, y)),
                             __fmul_rn(z, z));
        posq[i] = F4{x, y, z, sq};
    }
}

// ---------------------------------------------------------------------------
// knn_gemm: 512 blocks x 1024 threads (16 waves).
//   phase A: per-split top-16 distances; d2 values RETAINED in VGPRs (d2v[64])
//   merge:   16-way, wave 0, exact 16th smallest + per-split offsets
//            (pops in split order on ties == ascending-index tie rule)
//   phase B: emit indices from the d2v registers (no recompute, no restream)
//   phase C: bf16 MFMA gemm (4 m-tiles x 4 n-groups), LDS-staged stores
// ---------------------------------------------------------------------------
struct PA {                                      // knn phase (~68.3 KB)
    float lists[SPLITS][16][64];                 // 64 KB, lane-stride 1
    unsigned short offs[SPLITS][64];             // 2 KB
    unsigned short cnts[SPLITS][64];             // 2 KB
    float Tq[64];
};
struct PB {                                      // gemm staging (50688 B)
    unsigned short Ubuf[64][PADH];
    unsigned short Vbuf[64][PADH];
    unsigned short Sbuf[64][PADH];
};

__global__ __launch_bounds__(1024, 4) void knn_gemm_kernel(
    const F4* __restrict__ posq, const float* __restrict__ X,
    const unsigned short* __restrict__ WT, const float* __restrict__ bias,
    int* __restrict__ idx_out,
    unsigned short* __restrict__ U, unsigned short* __restrict__ V,
    unsigned short* __restrict__ S)
{
    __shared__ __align__(16) char smraw[sizeof(PA) > sizeof(PB) ? sizeof(PA) : sizeof(PB)];
    PA* A  = (PA*)smraw;
    PB* Bm = (PB*)smraw;                         // aliases PA after phase B

    int t = threadIdx.x;
    int q = t & 63;
    int s = __builtin_amdgcn_readfirstlane(t >> 6);   // wave id == split (uniform)
    int blk = blockIdx.x;
    int batch = blk >> 4;                        // 16 blocks per batch
    int qblk  = blk & 15;
    int iloc  = qblk * 64 + q;                   // query local index in batch

    const F4* __restrict__ pbq = posq + (size_t)batch * P;   // uniform base
    const int j0 = s * CPS;
    const F4* __restrict__ pcand = pbq + j0;     // uniform -> s_load stream

    F4 me = pbq[iloc];                           // per-lane (vector load)

    // ================= phase A: per-split top-16 values =================
    float d[16];
#pragma unroll
    for (int k = 0; k < 16; ++k) d[k] = FLT_MAX;
    float d2v[CPS];                              // retained for phase B

#pragma unroll
    for (int jj = 0; jj < CPS; ++jj) {
        F4 c = pcand[jj];
        float dot = __fadd_rn(__fadd_rn(__fmul_rn(me.x, c.x), __fmul_rn(me.y, c.y)),
                              __fmul_rn(me.z, c.z));
        float d2 = __fadd_rn(__fadd_rn(me.w, c.w), __fmul_rn(-2.0f, dot));
        if (j0 + jj == iloc) d2 = FLT_MAX;
        d2v[jj] = d2;
#pragma unroll
        for (int k = 15; k >= 1; --k)
            d[k] = __builtin_amdgcn_fmed3f(d[k - 1], d2, d[k]);
        d[0] = fminf(d[0], d2);
    }
#pragma unroll
    for (int k = 0; k < 16; ++k) A->lists[s][k][q] = d[k];
    __syncthreads();

    // ---- merge 16 sorted lists -> exact 16th smallest + per-split counts ---
    if (s == 0) {
#define DECL(i) float v##i = A->lists[i][0][q]; int n##i = 0;
        DECL(0) DECL(1) DECL(2) DECL(3) DECL(4) DECL(5) DECL(6) DECL(7)
        DECL(8) DECL(9) DECL(10) DECL(11) DECL(12) DECL(13) DECL(14) DECL(15)
#undef DECL
        float T = 0.0f;
#pragma unroll 1
        for (int k = 0; k < 16; ++k) {
            float mn = fminf(fminf(fminf(fminf(v0, v1), fminf(v2, v3)),
                                   fminf(fminf(v4, v5), fminf(v6, v7))),
                             fminf(fminf(fminf(v8, v9), fminf(v10, v11)),
                                   fminf(fminf(v12, v13), fminf(v14, v15))));
#define POP(i) (v##i == mn) { n##i++; v##i = (n##i < 16) ? A->lists[i][n##i][q] : FLT_MAX; }
            if      POP(0)  else if POP(1)  else if POP(2)  else if POP(3)
            else if POP(4)  else if POP(5)  else if POP(6)  else if POP(7)
            else if POP(8)  else if POP(9)  else if POP(10) else if POP(11)
            else if POP(12) else if POP(13) else if POP(14)
            else { n15++; v15 = (n15 < 16) ? A->lists[15][n15][q] : FLT_MAX; }
#undef POP
            T = mn;
        }
        A->Tq[q] = T;
        int off = 0;
#define EMIT(i) A->offs[i][q] = (unsigned short)off; A->cnts[i][q] = (unsigned short)n##i; off += n##i;
        EMIT(0) EMIT(1) EMIT(2) EMIT(3) EMIT(4) EMIT(5) EMIT(6) EMIT(7)
        EMIT(8) EMIT(9) EMIT(10) EMIT(11) EMIT(12) EMIT(13) EMIT(14) EMIT(15)
#undef EMIT
    }
    __syncthreads();

    // ========== phase B: emit indices straight from the d2v registers ======
    {
        float T   = A->Tq[q];
        int   cap = A->cnts[s][q];
        int   gb  = ((blk << 6) + q) * KNN + A->offs[s][q];
        int   base = batch * P + j0;
        int   cnt = 0;
#pragma unroll
        for (int jj = 0; jj < CPS; ++jj) {
            if (d2v[jj] <= T && cnt < cap) {
                idx_out[gb + cnt] = base + jj;
                cnt++;
            }
        }
    }
    __syncthreads();   // after this, smraw is repurposed as PB

    // ================= phase C: gemm =================
    {
        int mt = s & 3, ng = s >> 2;             // m-tile, n-group (6 tiles)
        int m0 = blk * 64 + mt * 16;
        int lm = q & 15, kg = q >> 4;

        const float4* arow = (const float4*)(X + (size_t)(m0 + lm) * 64 + kg * 8);
        float4 f0 = arow[0], f1 = arow[1];       // k = kg*8 .. +8
        float4 f2 = arow[8], f3 = arow[9];       // k = 32+kg*8 .. +8
        short8 a0, a1;
        a0[0] = (short)f2bf(f0.x); a0[1] = (short)f2bf(f0.y);
        a0[2] = (short)f2bf(f0.z); a0[3] = (short)f2bf(f0.w);
        a0[4] = (short)f2bf(f1.x); a0[5] = (short)f2bf(f1.y);
        a0[6] = (short)f2bf(f1.z); a0[7] = (short)f2bf(f1.w);
        a1[0] = (short)f2bf(f2.x); a1[1] = (short)f2bf(f2.y);
        a1[2] = (short)f2bf(f2.z); a1[3] = (short)f2bf(f2.w);
        a1[4] = (short)f2bf(f3.x); a1[5] = (short)f2bf(f3.y);
        a1[6] = (short)f2bf(f3.z); a1[7] = (short)f2bf(f3.w);

#pragma unroll 3
        for (int nt = ng * 6; nt < ng * 6 + 6; ++nt) {
            const short8* brow = (const short8*)(WT + (size_t)(nt * 16 + lm) * 64 + kg * 8);
            short8 b0 = brow[0];
            short8 b1 = brow[4];
            floatx4 acc = {0.0f, 0.0f, 0.0f, 0.0f};
            acc = __builtin_amdgcn_mfma_f32_16x16x32_bf16(a0, b0, acc, 0, 0, 0);
            acc = __builtin_amdgcn_mfma_f32_16x16x32_bf16(a1, b1, acc, 0, 0, 0);

            int col = nt * 16 + lm;
            float bv = bias[col];
#pragma unroll
            for (int r = 0; r < 4; ++r) {
                int row = mt * 16 + kg * 4 + r;
                unsigned short val = f2bf(acc[r] + bv);
                if (col < 128)      Bm->Ubuf[row][col] = val;
                else if (col < 256) Bm->Vbuf[row][col - 128] = val;
                else                Bm->Sbuf[row][col - 256] = val;
            }
        }
    }
    __syncthreads();

    // U/V/S: LDS -> global, fully coalesced (3 x 16 KB contiguous per block)
    {
        uint2* Ug = (uint2*)U + (size_t)blk * 2048;
        uint2* Vg = (uint2*)V + (size_t)blk * 2048;
        uint2* Sg = (uint2*)S + (size_t)blk * 2048;
#pragma unroll
        for (int i = t; i < 2048; i += 1024) {
            int row = i >> 5, off = (i & 31) * 4;
            Ug[i] = *(const uint2*)&Bm->Ubuf[row][off];
            Vg[i] = *(const uint2*)&Bm->Vbuf[row][off];
            Sg[i] = *(const uint2*)&Bm->Sbuf[row][off];
        }
    }
}

// ---------------------------------------------------------------------------
// final: out[p][h] = relu(U[p][h] + max_j V[nbr_j][h]) + S[p][h]  (write-only)
// ---------------------------------------------------------------------------
__global__ __launch_bounds__(256) void final_kernel(
    const int* __restrict__ idx, const unsigned short* __restrict__ U,
    const unsigned short* __restrict__ V, const unsigned short* __restrict__ S,
    float* __restrict__ out)
{
    int t = threadIdx.x;
    __shared__ int nbr[8][KNN];
    if (t < 128) ((int*)nbr)[t] = idx[(size_t)blockIdx.x * 128 + t];
    __syncthreads();

    int w = t >> 6, l = t & 63;
    int half = l >> 5, c4 = l & 31;              // c4 -> cols 4c4 .. 4c4+3
    int pl = w * 2 + half;                       // local point 0..7
    size_t p = (size_t)blockIdx.x * 8 + pl;

    uint2 uu = ((const uint2*)(U + p * H))[c4];
    uint2 ss = ((const uint2*)(S + p * H))[c4];

    float m0 = -FLT_MAX, m1 = -FLT_MAX, m2 = -FLT_MAX, m3 = -FLT_MAX;
#pragma unroll
    for (int k = 0; k < KNN; ++k) {
        int row = nbr[pl][k];
        uint2 vv = *(const uint2*)(V + (size_t)row * H + c4 * 4);
        m0 = fmaxf(m0, __uint_as_float(vv.x << 16));
        m1 = fmaxf(m1, __uint_as_float(vv.x & 0xFFFF0000u));
        m2 = fmaxf(m2, __uint_as_float(vv.y << 16));
        m3 = fmaxf(m3, __uint_as_float(vv.y & 0xFFFF0000u));
    }

    float4 o;
    o.x = fmaxf(__uint_as_float(uu.x << 16)          + m0, 0.0f) + __uint_as_float(ss.x << 16);
    o.y = fmaxf(__uint_as_float(uu.x & 0xFFFF0000u)  + m1, 0.0f) + __uint_as_float(ss.x & 0xFFFF0000u);
    o.z = fmaxf(__uint_as_float(uu.y << 16)          + m2, 0.0f) + __uint_as_float(ss.y << 16);
    o.w = fmaxf(__uint_as_float(uu.y & 0xFFFF0000u)  + m3, 0.0f) + __uint_as_float(ss.y & 0xFFFF0000u);
    ((float4*)(out + p * H))[c4] = o;
}

// ---------------------------------------------------------------------------
extern "C" void kernel_launch(void* const* d_in, const int* in_sizes, int n_in,
                              void* d_out, int out_size, void* d_ws, size_t ws_size,
                              hipStream_t stream)
{
    const float* x    = (const float*)d_in[0];
    const float* pos  = (const float*)d_in[1];
    // d_in[2] = batch indices (implicit: i / P) -- unused
    const float* W_e  = (const float*)d_in[3];
    const float* b_e  = (const float*)d_in[4];
    const float* W_sc = (const float*)d_in[5];
    const float* b_sc = (const float*)d_in[6];
    float* out = (float*)d_out;

    char* ws = (char*)d_ws;
    // workspace layout (bytes)
    const size_t OFF_IDX  = 0;                          // N*K*4 = 2 MB
    const size_t OFF_U    = 2ull << 20;                 // N*H*2 = 8 MB
    const size_t OFF_V    = OFF_U + (8ull << 20);       // 8 MB
    const size_t OFF_S    = OFF_V + (8ull << 20);       // 8 MB
    const size_t OFF_PQ   = OFF_S + (8ull << 20);       // N*16 = 512 KB
    const size_t OFF_WT   = OFF_PQ + (512ull << 10);    // 384*64*2 = 48 KB
    const size_t OFF_BIAS = OFF_WT + 49152;             // 384*4

    int*            idx  = (int*)(ws + OFF_IDX);
    unsigned short* U    = (unsigned short*)(ws + OFF_U);
    unsigned short* V    = (unsigned short*)(ws + OFF_V);
    unsigned short* S    = (unsigned short*)(ws + OFF_S);
    F4*             posq = (F4*)(ws + OFF_PQ);
    unsigned short* WT   = (unsigned short*)(ws + OFF_WT);
    float*          bias = (float*)(ws + OFF_BIAS);

    prep_kernel<<<224, 256, 0, stream>>>(W_e, b_e, W_sc, b_sc, pos, WT, bias, posq);
    knn_gemm_kernel<<<512, 1024, 0, stream>>>(posq, x, WT, bias, idx, U, V, S);
    final_kernel<<<N / 8, 256, 0, stream>>>(idx, U, V, S, out);
}

// Round 9
// 145.670 us; speedup vs baseline: 1.0883x; 1.0883x over previous
//
#include <hip/hip_runtime.h>
#include <float.h>
#include <stdint.h>

// Problem constants
#define BATCHES 32
#define P 1024
#define KNN 16
#define C 64
#define H 128
#define N (BATCHES * P)   // 32768
#define NCOLS 384         // U(128) | V(128) | S(128)
#define SPLITS 8
#define CPS 128           // candidates per split (P / SPLITS)
#define PADH 132          // LDS row pad for gemm staging

typedef short short8 __attribute__((ext_vector_type(8)));
typedef float floatx4 __attribute__((ext_vector_type(4)));
typedef float float2v __attribute__((ext_vector_type(2)));

__device__ __forceinline__ unsigned short f2bf(float f) {
    unsigned u = __float_as_uint(f);
    unsigned r = (u + 0x7FFF + ((u >> 16) & 1)) >> 16;   // RNE
    return (unsigned short)r;
}

struct alignas(16) F4 { float x, y, z, w; };

// ---------------------------------------------------------------------------
// prep_w: build WcatT (bf16, [384][64]) and bias_cat (fp32, [384])
// ---------------------------------------------------------------------------
__global__ __launch_bounds__(256) void prep_w(
    const float* __restrict__ W_e, const float* __restrict__ b_e,
    const float* __restrict__ W_sc, const float* __restrict__ b_sc,
    unsigned short* __restrict__ WT, float* __restrict__ bias)
{
    int i = blockIdx.x * 256 + threadIdx.x;      // 0 .. 384*64-1
    int col = i >> 6, c = i & 63;
    float w;
    if (col < 128)      w = W_e[c * 128 + col] - W_e[(64 + c) * 128 + col];
    else if (col < 256) w = W_e[(64 + c) * 128 + (col - 128)];
    else                w = W_sc[c * 128 + (col - 256)];
    WT[col * 64 + c] = f2bf(w);
    if (c == 0) {
        bias[col] = (col < 128) ? b_e[col] : (col < 256 ? 0.0f : b_sc[col - 256]);
    }
}

// ---------------------------------------------------------------------------
// knn_gemm (R5 structure == best measured 62.4us, + packed-fp32 distance):
//   phase A: per-split top-16 via med3 ladder; dist computed for 2 candidates
//            per iteration as float2 (v_pk_mul/add_f32), contract(off) ->
//            per-component rounding bit-identical to the scalar __f*_rn chain
//   merge:   8-way heads-in-regs, exact 16th smallest + per-split offsets
//   phase B: paired dist recompute, emit indices directly to global
//   phase C: bf16 MFMA gemm, LDS-staged, coalesced U/V/S stores
// 512 blocks x 512 threads.
// ---------------------------------------------------------------------------
struct PA {                                      // knn phase (~51.6 KB)
    F4    spos[P + 8];                           // +8 pad for prefetch overrun
    float lists[SPLITS][16][64];                 // 32 KB, lane-stride 1
    unsigned short offs[SPLITS][64];
    unsigned short cnts[SPLITS][64];
    float Tq[64];
};
struct PB {                                      // gemm staging (50688 B)
    unsigned short Ubuf[64][PADH];
    unsigned short Vbuf[64][PADH];
    unsigned short Sbuf[64][PADH];
};

__global__ __launch_bounds__(512) void knn_gemm_kernel(
    const float* __restrict__ pos, const float* __restrict__ X,
    const unsigned short* __restrict__ WT, const float* __restrict__ bias,
    int* __restrict__ idx_out,
    unsigned short* __restrict__ U, unsigned short* __restrict__ V,
    unsigned short* __restrict__ S)
{
#pragma clang fp contract(off)
    __shared__ __align__(16) char smraw[sizeof(PA)];
    PA* A  = (PA*)smraw;
    PB* Bm = (PB*)smraw;                         // aliases PA after phase B

    int t = threadIdx.x;
    int q = t & 63, s = t >> 6;                  // s == wave id == split
    int blk = blockIdx.x;
    int batch = blk >> 4;                        // 16 blocks per batch
    int qblk  = blk & 15;
    int iloc  = qblk * 64 + q;                   // query local index in batch

    // ---- stage spos ----
    const float* pb = pos + (size_t)batch * P * 3;
    for (int j = t; j < P; j += 512) {
        float x = pb[j * 3 + 0], y = pb[j * 3 + 1], z = pb[j * 3 + 2];
        float sq = __fadd_rn(__fadd_rn(__fmul_rn(x, x), __fmul_rn(y, y)),
                             __fmul_rn(z, z));
        A->spos[j] = F4{x, y, z, sq};
    }
    __syncthreads();

    F4 me = A->spos[iloc];
    const float2v mex = {me.x, me.x}, mey = {me.y, me.y};
    const float2v mez = {me.z, me.z}, mew = {me.w, me.w};
    const float2v m2  = {-2.0f, -2.0f};
    const int j0 = s * CPS;

    // ================= phase A: per-split top-16 values =================
    float d[16];
#pragma unroll
    for (int k = 0; k < 16; ++k) d[k] = FLT_MAX;

    {
        F4 pa = A->spos[j0 + 0], pc = A->spos[j0 + 1];
#pragma unroll 4
        for (int jj = 0; jj < CPS; jj += 2) {
            F4 na = A->spos[j0 + jj + 2];
            F4 nb = A->spos[j0 + jj + 3];
            float2v cx = {pa.x, pc.x}, cy = {pa.y, pc.y};
            float2v cz = {pa.z, pc.z}, cw = {pa.w, pc.w};
            float2v dot = (mex * cx + mey * cy) + mez * cz;   // pk mul/add
            float2v d2p = (mew + cw) + m2 * dot;
            float d2a = d2p.x, d2b = d2p.y;
            if (j0 + jj     == iloc) d2a = FLT_MAX;
            if (j0 + jj + 1 == iloc) d2b = FLT_MAX;
#pragma unroll
            for (int k = 15; k >= 1; --k)
                d[k] = __builtin_amdgcn_fmed3f(d[k - 1], d2a, d[k]);
            d[0] = fminf(d[0], d2a);
#pragma unroll
            for (int k = 15; k >= 1; --k)
                d[k] = __builtin_amdgcn_fmed3f(d[k - 1], d2b, d[k]);
            d[0] = fminf(d[0], d2b);
            pa = na; pc = nb;
        }
    }
#pragma unroll
    for (int k = 0; k < 16; ++k) A->lists[s][k][q] = d[k];
    __syncthreads();

    // ---- merge 8 sorted lists -> exact 16th smallest + per-split counts ----
    // Pops in split order on value ties == ascending-index tie rule.
    if (s == 0) {
        float v0 = A->lists[0][0][q], v1 = A->lists[1][0][q];
        float v2 = A->lists[2][0][q], v3 = A->lists[3][0][q];
        float v4 = A->lists[4][0][q], v5 = A->lists[5][0][q];
        float v6 = A->lists[6][0][q], v7 = A->lists[7][0][q];
        float w0 = A->lists[0][1][q], w1 = A->lists[1][1][q];
        float w2 = A->lists[2][1][q], w3 = A->lists[3][1][q];
        float w4 = A->lists[4][1][q], w5 = A->lists[5][1][q];
        float w6 = A->lists[6][1][q], w7 = A->lists[7][1][q];
        int n0 = 0, n1 = 0, n2 = 0, n3 = 0, n4 = 0, n5 = 0, n6 = 0, n7 = 0;
        float T = 0.0f;
#pragma unroll 1
        for (int k = 0; k < 16; ++k) {
            float mn = fminf(fminf(fminf(v0, v1), fminf(v2, v3)),
                             fminf(fminf(v4, v5), fminf(v6, v7)));
            if      (v0 == mn) { n0++; v0 = w0; w0 = (n0 + 1 < 16) ? A->lists[0][n0 + 1][q] : FLT_MAX; }
            else if (v1 == mn) { n1++; v1 = w1; w1 = (n1 + 1 < 16) ? A->lists[1][n1 + 1][q] : FLT_MAX; }
            else if (v2 == mn) { n2++; v2 = w2; w2 = (n2 + 1 < 16) ? A->lists[2][n2 + 1][q] : FLT_MAX; }
            else if (v3 == mn) { n3++; v3 = w3; w3 = (n3 + 1 < 16) ? A->lists[3][n3 + 1][q] : FLT_MAX; }
            else if (v4 == mn) { n4++; v4 = w4; w4 = (n4 + 1 < 16) ? A->lists[4][n4 + 1][q] : FLT_MAX; }
            else if (v5 == mn) { n5++; v5 = w5; w5 = (n5 + 1 < 16) ? A->lists[5][n5 + 1][q] : FLT_MAX; }
            else if (v6 == mn) { n6++; v6 = w6; w6 = (n6 + 1 < 16) ? A->lists[6][n6 + 1][q] : FLT_MAX; }
            else               { n7++; v7 = w7; w7 = (n7 + 1 < 16) ? A->lists[7][n7 + 1][q] : FLT_MAX; }
            T = mn;
        }
        A->Tq[q] = T;
        int off = 0;
        A->offs[0][q] = (unsigned short)off; A->cnts[0][q] = (unsigned short)n0; off += n0;
        A->offs[1][q] = (unsigned short)off; A->cnts[1][q] = (unsigned short)n1; off += n1;
        A->offs[2][q] = (unsigned short)off; A->cnts[2][q] = (unsigned short)n2; off += n2;
        A->offs[3][q] = (unsigned short)off; A->cnts[3][q] = (unsigned short)n3; off += n3;
        A->offs[4][q] = (unsigned short)off; A->cnts[4][q] = (unsigned short)n4; off += n4;
        A->offs[5][q] = (unsigned short)off; A->cnts[5][q] = (unsigned short)n5; off += n5;
        A->offs[6][q] = (unsigned short)off; A->cnts[6][q] = (unsigned short)n6; off += n6;
        A->offs[7][q] = (unsigned short)off; A->cnts[7][q] = (unsigned short)n7;
    }
    __syncthreads();

    // ================= phase B: emit indices directly to global =============
    {
        float T   = A->Tq[q];
        int   cap = A->cnts[s][q];
        int   gb  = ((blk << 6) + q) * KNN + A->offs[s][q];
        int   base = batch * P + j0;
        int   cnt = 0;

        F4 pa = A->spos[j0 + 0], pc = A->spos[j0 + 1];
#pragma unroll 2
        for (int jj = 0; jj < CPS; jj += 2) {
            F4 na = A->spos[j0 + jj + 2];
            F4 nb = A->spos[j0 + jj + 3];
            float2v cx = {pa.x, pc.x}, cy = {pa.y, pc.y};
            float2v cz = {pa.z, pc.z}, cw = {pa.w, pc.w};
            float2v dot = (mex * cx + mey * cy) + mez * cz;
            float2v d2p = (mew + cw) + m2 * dot;
            float d2a = d2p.x, d2b = d2p.y;
            if (j0 + jj     == iloc) d2a = FLT_MAX;
            if (j0 + jj + 1 == iloc) d2b = FLT_MAX;
            if (d2a <= T && cnt < cap) { idx_out[gb + cnt] = base + jj;     cnt++; }
            if (d2b <= T && cnt < cap) { idx_out[gb + cnt] = base + jj + 1; cnt++; }
            pa = na; pc = nb;
        }
    }
    __syncthreads();   // after this, smraw is repurposed as PB

    // ================= phase C: gemm =================
    {
        int mt = s & 3, nh = s >> 2;             // m-tile, n-half
        int m0 = blk * 64 + mt * 16;
        int lm = q & 15, kg = q >> 4;

        const float4* arow = (const float4*)(X + (size_t)(m0 + lm) * 64 + kg * 8);
        float4 f0 = arow[0], f1 = arow[1];       // k = kg*8 .. +8
        float4 f2 = arow[8], f3 = arow[9];       // k = 32+kg*8 .. +8
        short8 a0, a1;
        a0[0] = (short)f2bf(f0.x); a0[1] = (short)f2bf(f0.y);
        a0[2] = (short)f2bf(f0.z); a0[3] = (short)f2bf(f0.w);
        a0[4] = (short)f2bf(f1.x); a0[5] = (short)f2bf(f1.y);
        a0[6] = (short)f2bf(f1.z); a0[7] = (short)f2bf(f1.w);
        a1[0] = (short)f2bf(f2.x); a1[1] = (short)f2bf(f2.y);
        a1[2] = (short)f2bf(f2.z); a1[3] = (short)f2bf(f2.w);
        a1[4] = (short)f2bf(f3.x); a1[5] = (short)f2bf(f3.y);
        a1[6] = (short)f2bf(f3.z); a1[7] = (short)f2bf(f3.w);

#pragma unroll 4
        for (int nt = nh * 12; nt < nh * 12 + 12; ++nt) {
            const short8* brow = (const short8*)(WT + (size_t)(nt * 16 + lm) * 64 + kg * 8);
            short8 b0 = brow[0];
            short8 b1 = brow[4];
            floatx4 acc = {0.0f, 0.0f, 0.0f, 0.0f};
            acc = __builtin_amdgcn_mfma_f32_16x16x32_bf16(a0, b0, acc, 0, 0, 0);
            acc = __builtin_amdgcn_mfma_f32_16x16x32_bf16(a1, b1, acc, 0, 0, 0);

            int col = nt * 16 + lm;
            float bv = bias[col];
#pragma unroll
            for (int r = 0; r < 4; ++r) {
                int row = mt * 16 + kg * 4 + r;
                unsigned short val = f2bf(acc[r] + bv);
                if (col < 128)      Bm->Ubuf[row][col] = val;
                else if (col < 256) Bm->Vbuf[row][col - 128] = val;
                else                Bm->Sbuf[row][col - 256] = val;
            }
        }
    }
    __syncthreads();

    // U/V/S: LDS -> global, fully coalesced (3 x 16 KB contiguous per block)
    {
        uint2* Ug = (uint2*)U + (size_t)blk * 2048;
        uint2* Vg = (uint2*)V + (size_t)blk * 2048;
        uint2* Sg = (uint2*)S + (size_t)blk * 2048;
#pragma unroll
        for (int i = t; i < 2048; i += 512) {
            int row = i >> 5, off = (i & 31) * 4;
            Ug[i] = *(const uint2*)&Bm->Ubuf[row][off];
            Vg[i] = *(const uint2*)&Bm->Vbuf[row][off];
            Sg[i] = *(const uint2*)&Bm->Sbuf[row][off];
        }
    }
}

// ---------------------------------------------------------------------------
// final: out[p][h] = relu(U[p][h] + max_j V[nbr_j][h]) + S[p][h]  (write-only)
// ---------------------------------------------------------------------------
__global__ __launch_bounds__(256) void final_kernel(
    const int* __restrict__ idx, const unsigned short* __restrict__ U,
    const unsigned short* __restrict__ V, const unsigned short* __restrict__ S,
    float* __restrict__ out)
{
    int t = threadIdx.x;
    __shared__ int nbr[8][KNN];
    if (t < 128) ((int*)nbr)[t] = idx[(size_t)blockIdx.x * 128 + t];
    __syncthreads();

    int w = t >> 6, l = t & 63;
    int half = l >> 5, c4 = l & 31;              // c4 -> cols 4c4 .. 4c4+3
    int pl = w * 2 + half;                       // local point 0..7
    size_t p = (size_t)blockIdx.x * 8 + pl;

    uint2 uu = ((const uint2*)(U + p * H))[c4];
    uint2 ss = ((const uint2*)(S + p * H))[c4];

    float m0 = -FLT_MAX, m1 = -FLT_MAX, m2 = -FLT_MAX, m3 = -FLT_MAX;
#pragma unroll
    for (int k = 0; k < KNN; ++k) {
        int row = nbr[pl][k];
        uint2 vv = *(const uint2*)(V + (size_t)row * H + c4 * 4);
        m0 = fmaxf(m0, __uint_as_float(vv.x << 16));
        m1 = fmaxf(m1, __uint_as_float(vv.x & 0xFFFF0000u));
        m2 = fmaxf(m2, __uint_as_float(vv.y << 16));
        m3 = fmaxf(m3, __uint_as_float(vv.y & 0xFFFF0000u));
    }

    float4 o;
    o.x = fmaxf(__uint_as_float(uu.x << 16)          + m0, 0.0f) + __uint_as_float(ss.x << 16);
    o.y = fmaxf(__uint_as_float(uu.x & 0xFFFF0000u)  + m1, 0.0f) + __uint_as_float(ss.x & 0xFFFF0000u);
    o.z = fmaxf(__uint_as_float(uu.y << 16)          + m2, 0.0f) + __uint_as_float(ss.y << 16);
    o.w = fmaxf(__uint_as_float(uu.y & 0xFFFF0000u)  + m3, 0.0f) + __uint_as_float(ss.y & 0xFFFF0000u);
    ((float4*)(out + p * H))[c4] = o;
}

// ---------------------------------------------------------------------------
extern "C" void kernel_launch(void* const* d_in, const int* in_sizes, int n_in,
                              void* d_out, int out_size, void* d_ws, size_t ws_size,
                              hipStream_t stream)
{
    const float* x    = (const float*)d_in[0];
    const float* pos  = (const float*)d_in[1];
    // d_in[2] = batch indices (implicit: i / P) -- unused
    const float* W_e  = (const float*)d_in[3];
    const float* b_e  = (const float*)d_in[4];
    const float* W_sc = (const float*)d_in[5];
    const float* b_sc = (const float*)d_in[6];
    float* out = (float*)d_out;

    char* ws = (char*)d_ws;
    // workspace layout (bytes)
    const size_t OFF_IDX  = 0;                          // N*K*4 = 2 MB
    const size_t OFF_U    = 2ull << 20;                 // N*H*2 = 8 MB
    const size_t OFF_V    = OFF_U + (8ull << 20);       // 8 MB
    const size_t OFF_S    = OFF_V + (8ull << 20);       // 8 MB
    const size_t OFF_WT   = OFF_S + (8ull << 20);       // 384*64*2 = 48 KB
    const size_t OFF_BIAS = OFF_WT + 49152;             // 384*4

    int*            idx  = (int*)(ws + OFF_IDX);
    unsigned short* U    = (unsigned short*)(ws + OFF_U);
    unsigned short* V    = (unsigned short*)(ws + OFF_V);
    unsigned short* S    = (unsigned short*)(ws + OFF_S);
    unsigned short* WT   = (unsigned short*)(ws + OFF_WT);
    float*          bias = (float*)(ws + OFF_BIAS);

    prep_w<<<(NCOLS * C) / 256, 256, 0, stream>>>(W_e, b_e, W_sc, b_sc, WT, bias);
    knn_gemm_kernel<<<512, 512, 0, stream>>>(pos, x, WT, bias, idx, U, V, S);
    final_kernel<<<N / 8, 256, 0, stream>>>(idx, U, V, S, out);
}

// Round 10
// 142.350 us; speedup vs baseline: 1.1137x; 1.0233x over previous
//
#include <hip/hip_runtime.h>
#include <float.h>
#include <stdint.h>

// Problem constants
#define BATCHES 32
#define P 1024
#define KNN 16
#define C 64
#define H 128
#define N (BATCHES * P)   // 32768
#define NCOLS 384         // U(128) | V(128) | S(128)
#define SPLITS 8
#define CPS 128           // candidates per split (P / SPLITS)
#define PADH 132          // LDS row pad for gemm staging

typedef short short8 __attribute__((ext_vector_type(8)));
typedef float floatx4 __attribute__((ext_vector_type(4)));

__device__ __forceinline__ unsigned short f2bf(float f) {
    unsigned u = __float_as_uint(f);
    unsigned r = (u + 0x7FFF + ((u >> 16) & 1)) >> 16;   // RNE
    return (unsigned short)r;
}

// ---------------------------------------------------------------------------
// prep_w: build WcatT (bf16, [384][64]) and bias_cat (fp32, [384])
// ---------------------------------------------------------------------------
__global__ __launch_bounds__(256) void prep_w(
    const float* __restrict__ W_e, const float* __restrict__ b_e,
    const float* __restrict__ W_sc, const float* __restrict__ b_sc,
    unsigned short* __restrict__ WT, float* __restrict__ bias)
{
    int i = blockIdx.x * 256 + threadIdx.x;      // 0 .. 384*64-1
    int col = i >> 6, c = i & 63;
    float w;
    if (col < 128)      w = W_e[c * 128 + col] - W_e[(64 + c) * 128 + col];
    else if (col < 256) w = W_e[(64 + c) * 128 + (col - 128)];
    else                w = W_sc[c * 128 + (col - 256)];
    WT[col * 64 + c] = f2bf(w);
    if (c == 0) {
        bias[col] = (col < 128) ? b_e[col] : (col < 256 ? 0.0f : b_sc[col - 256]);
    }
}

// ---------------------------------------------------------------------------
// knn_gemm (measured-best variant, 62.4 us):
//   phase A = per-split top-16 via med3 ladder, 4-deep spos prefetch
//   merge   = 8-way heads-in-regs, exact 16th smallest + per-split offsets
//             (pops in split order on ties == ascending-index tie rule)
//   phase B = recompute dist, emit indices directly to global
//   phase C = bf16 MFMA gemm, LDS-staged, coalesced U/V/S stores
// 512 blocks x 512 threads.
// ---------------------------------------------------------------------------
struct alignas(16) F4 { float x, y, z, w; };

struct PA {                                      // knn phase (51584 B)
    F4    spos[P + 8];                           // +8 pad for prefetch overrun
    float lists[SPLITS][16][64];                 // 32 KB, lane-stride 1
    unsigned short offs[SPLITS][64];             // output offset per (split,q)
    unsigned short cnts[SPLITS][64];             // pop count  per (split,q)
    float Tq[64];
};
struct PB {                                      // gemm staging (50688 B)
    unsigned short Ubuf[64][PADH];
    unsigned short Vbuf[64][PADH];
    unsigned short Sbuf[64][PADH];
};

__global__ __launch_bounds__(512) void knn_gemm_kernel(
    const float* __restrict__ pos, const float* __restrict__ X,
    const unsigned short* __restrict__ WT, const float* __restrict__ bias,
    int* __restrict__ idx_out,
    unsigned short* __restrict__ U, unsigned short* __restrict__ V,
    unsigned short* __restrict__ S)
{
    __shared__ __align__(16) char smraw[sizeof(PA)];
    PA* A  = (PA*)smraw;
    PB* Bm = (PB*)smraw;                         // aliases PA after phase B

    int t = threadIdx.x;
    int q = t & 63, s = t >> 6;                  // s == wave id == split
    int blk = blockIdx.x;
    int batch = blk >> 4;                        // 16 blocks per batch
    int qblk  = blk & 15;
    int iloc  = qblk * 64 + q;                   // query local index in batch

    // ---- stage spos ----
    const float* pb = pos + (size_t)batch * P * 3;
    for (int j = t; j < P; j += 512) {
        float x = pb[j * 3 + 0], y = pb[j * 3 + 1], z = pb[j * 3 + 2];
        float sq = __fadd_rn(__fadd_rn(__fmul_rn(x, x), __fmul_rn(y, y)),
                             __fmul_rn(z, z));
        A->spos[j] = F4{x, y, z, sq};
    }
    __syncthreads();

    F4 me = A->spos[iloc];
    const int j0 = s * CPS;

    // ================= phase A: per-split top-16 values =================
    float d[16];
#pragma unroll
    for (int k = 0; k < 16; ++k) d[k] = FLT_MAX;

    auto dist = [&](const F4& c, int j) -> float {
        float dot = __fadd_rn(__fadd_rn(__fmul_rn(me.x, c.x), __fmul_rn(me.y, c.y)),
                              __fmul_rn(me.z, c.z));
        float d2 = __fadd_rn(__fadd_rn(me.w, c.w), __fmul_rn(-2.0f, dot));
        return (j == iloc) ? FLT_MAX : d2;
    };
    auto insert = [&](float d2) {
#pragma unroll
        for (int k = 15; k >= 1; --k)
            d[k] = __builtin_amdgcn_fmed3f(d[k - 1], d2, d[k]);
        d[0] = fminf(d[0], d2);
    };

    {
        F4 c0 = A->spos[j0 + 0], c1 = A->spos[j0 + 1];
        F4 c2 = A->spos[j0 + 2], c3 = A->spos[j0 + 3];
#pragma unroll 2
        for (int jj = 0; jj < CPS; jj += 4) {
            F4 n0 = A->spos[j0 + jj + 4];
            F4 n1 = A->spos[j0 + jj + 5];
            F4 n2 = A->spos[j0 + jj + 6];
            F4 n3 = A->spos[j0 + jj + 7];
            insert(dist(c0, j0 + jj + 0));
            insert(dist(c1, j0 + jj + 1));
            insert(dist(c2, j0 + jj + 2));
            insert(dist(c3, j0 + jj + 3));
            c0 = n0; c1 = n1; c2 = n2; c3 = n3;
        }
    }
#pragma unroll
    for (int k = 0; k < 16; ++k) A->lists[s][k][q] = d[k];
    __syncthreads();

    // ---- merge 8 sorted lists -> exact 16th smallest + per-split counts ----
    // Pops in split order on value ties == ascending-index tie rule.
    if (s == 0) {
        float v0 = A->lists[0][0][q], v1 = A->lists[1][0][q];
        float v2 = A->lists[2][0][q], v3 = A->lists[3][0][q];
        float v4 = A->lists[4][0][q], v5 = A->lists[5][0][q];
        float v6 = A->lists[6][0][q], v7 = A->lists[7][0][q];
        float w0 = A->lists[0][1][q], w1 = A->lists[1][1][q];
        float w2 = A->lists[2][1][q], w3 = A->lists[3][1][q];
        float w4 = A->lists[4][1][q], w5 = A->lists[5][1][q];
        float w6 = A->lists[6][1][q], w7 = A->lists[7][1][q];
        int n0 = 0, n1 = 0, n2 = 0, n3 = 0, n4 = 0, n5 = 0, n6 = 0, n7 = 0;
        float T = 0.0f;
#pragma unroll 1
        for (int k = 0; k < 16; ++k) {
            float mn = fminf(fminf(fminf(v0, v1), fminf(v2, v3)),
                             fminf(fminf(v4, v5), fminf(v6, v7)));
            if      (v0 == mn) { n0++; v0 = w0; w0 = (n0 + 1 < 16) ? A->lists[0][n0 + 1][q] : FLT_MAX; }
            else if (v1 == mn) { n1++; v1 = w1; w1 = (n1 + 1 < 16) ? A->lists[1][n1 + 1][q] : FLT_MAX; }
            else if (v2 == mn) { n2++; v2 = w2; w2 = (n2 + 1 < 16) ? A->lists[2][n2 + 1][q] : FLT_MAX; }
            else if (v3 == mn) { n3++; v3 = w3; w3 = (n3 + 1 < 16) ? A->lists[3][n3 + 1][q] : FLT_MAX; }
            else if (v4 == mn) { n4++; v4 = w4; w4 = (n4 + 1 < 16) ? A->lists[4][n4 + 1][q] : FLT_MAX; }
            else if (v5 == mn) { n5++; v5 = w5; w5 = (n5 + 1 < 16) ? A->lists[5][n5 + 1][q] : FLT_MAX; }
            else if (v6 == mn) { n6++; v6 = w6; w6 = (n6 + 1 < 16) ? A->lists[6][n6 + 1][q] : FLT_MAX; }
            else               { n7++; v7 = w7; w7 = (n7 + 1 < 16) ? A->lists[7][n7 + 1][q] : FLT_MAX; }
            T = mn;
        }
        A->Tq[q] = T;
        int off = 0;
        A->offs[0][q] = (unsigned short)off; A->cnts[0][q] = (unsigned short)n0; off += n0;
        A->offs[1][q] = (unsigned short)off; A->cnts[1][q] = (unsigned short)n1; off += n1;
        A->offs[2][q] = (unsigned short)off; A->cnts[2][q] = (unsigned short)n2; off += n2;
        A->offs[3][q] = (unsigned short)off; A->cnts[3][q] = (unsigned short)n3; off += n3;
        A->offs[4][q] = (unsigned short)off; A->cnts[4][q] = (unsigned short)n4; off += n4;
        A->offs[5][q] = (unsigned short)off; A->cnts[5][q] = (unsigned short)n5; off += n5;
        A->offs[6][q] = (unsigned short)off; A->cnts[6][q] = (unsigned short)n6; off += n6;
        A->offs[7][q] = (unsigned short)off; A->cnts[7][q] = (unsigned short)n7;
    }
    __syncthreads();

    // ================= phase B: emit indices directly to global =============
    {
        float T  = A->Tq[q];
        int   cap = A->cnts[s][q];
        int   gb  = ((blk << 6) + q) * KNN + A->offs[s][q];
        int   base = batch * P;
        int   cnt = 0;

        F4 c0 = A->spos[j0 + 0], c1 = A->spos[j0 + 1];
        F4 c2 = A->spos[j0 + 2], c3 = A->spos[j0 + 3];
#pragma unroll 2
        for (int jj = 0; jj < CPS; jj += 4) {
            F4 n0 = A->spos[j0 + jj + 4];
            F4 n1 = A->spos[j0 + jj + 5];
            F4 n2 = A->spos[j0 + jj + 6];
            F4 n3 = A->spos[j0 + jj + 7];
#pragma unroll
            for (int u = 0; u < 4; ++u) {
                const F4& c = (u == 0) ? c0 : (u == 1) ? c1 : (u == 2) ? c2 : c3;
                int j = j0 + jj + u;
                float d2 = dist(c, j);
                if (d2 <= T && cnt < cap) {
                    idx_out[gb + cnt] = base + j;
                    cnt++;
                }
            }
            c0 = n0; c1 = n1; c2 = n2; c3 = n3;
        }
    }
    __syncthreads();   // after this, smraw is repurposed as PB

    // ================= phase C: gemm =================
    {
        int mt = s & 3, nh = s >> 2;             // m-tile, n-half
        int m0 = blk * 64 + mt * 16;
        int lm = q & 15, kg = q >> 4;

        const float4* arow = (const float4*)(X + (size_t)(m0 + lm) * 64 + kg * 8);
        float4 f0 = arow[0], f1 = arow[1];       // k = kg*8 .. +8
        float4 f2 = arow[8], f3 = arow[9];       // k = 32+kg*8 .. +8
        short8 a0, a1;
        a0[0] = (short)f2bf(f0.x); a0[1] = (short)f2bf(f0.y);
        a0[2] = (short)f2bf(f0.z); a0[3] = (short)f2bf(f0.w);
        a0[4] = (short)f2bf(f1.x); a0[5] = (short)f2bf(f1.y);
        a0[6] = (short)f2bf(f1.z); a0[7] = (short)f2bf(f1.w);
        a1[0] = (short)f2bf(f2.x); a1[1] = (short)f2bf(f2.y);
        a1[2] = (short)f2bf(f2.z); a1[3] = (short)f2bf(f2.w);
        a1[4] = (short)f2bf(f3.x); a1[5] = (short)f2bf(f3.y);
        a1[6] = (short)f2bf(f3.z); a1[7] = (short)f2bf(f3.w);

#pragma unroll 4
        for (int nt = nh * 12; nt < nh * 12 + 12; ++nt) {
            const short8* brow = (const short8*)(WT + (size_t)(nt * 16 + lm) * 64 + kg * 8);
            short8 b0 = brow[0];
            short8 b1 = brow[4];
            floatx4 acc = {0.0f, 0.0f, 0.0f, 0.0f};
            acc = __builtin_amdgcn_mfma_f32_16x16x32_bf16(a0, b0, acc, 0, 0, 0);
            acc = __builtin_amdgcn_mfma_f32_16x16x32_bf16(a1, b1, acc, 0, 0, 0);

            int col = nt * 16 + lm;
            float bv = bias[col];
#pragma unroll
            for (int r = 0; r < 4; ++r) {
                int row = mt * 16 + kg * 4 + r;
                unsigned short val = f2bf(acc[r] + bv);
                if (col < 128)      Bm->Ubuf[row][col] = val;
                else if (col < 256) Bm->Vbuf[row][col - 128] = val;
                else                Bm->Sbuf[row][col - 256] = val;
            }
        }
    }
    __syncthreads();

    // U/V/S: LDS -> global, fully coalesced (3 x 16 KB contiguous per block)
    {
        uint2* Ug = (uint2*)U + (size_t)blk * 2048;
        uint2* Vg = (uint2*)V + (size_t)blk * 2048;
        uint2* Sg = (uint2*)S + (size_t)blk * 2048;
#pragma unroll
        for (int i = t; i < 2048; i += 512) {
            int row = i >> 5, off = (i & 31) * 4;
            Ug[i] = *(const uint2*)&Bm->Ubuf[row][off];
            Vg[i] = *(const uint2*)&Bm->Vbuf[row][off];
            Sg[i] = *(const uint2*)&Bm->Sbuf[row][off];
        }
    }
}

// ---------------------------------------------------------------------------
// final: out[p][h] = relu(U[p][h] + max_j V[nbr_j][h]) + S[p][h]  (write-only)
// Block = 16 points x 16 lanes; each lane covers 8 cols via uint4 (16 B)
// gathers -- half the VMEM instruction count of the uint2 version.
// ---------------------------------------------------------------------------
__global__ __launch_bounds__(256) void final_kernel(
    const int* __restrict__ idx, const unsigned short* __restrict__ U,
    const unsigned short* __restrict__ V, const unsigned short* __restrict__ S,
    float* __restrict__ out)
{
    int t = threadIdx.x;
    __shared__ int nbr[16][KNN];
    ((int*)nbr)[t] = idx[(size_t)blockIdx.x * 256 + t];
    __syncthreads();

    int pl = t >> 4;                             // local point 0..15
    int c8 = t & 15;                             // cols 8*c8 .. 8*c8+7
    size_t p = (size_t)blockIdx.x * 16 + pl;

    uint4 uu = ((const uint4*)(U + p * H))[c8];
    uint4 ss = ((const uint4*)(S + p * H))[c8];

    float m0 = -FLT_MAX, m1 = -FLT_MAX, m2 = -FLT_MAX, m3 = -FLT_MAX;
    float m4 = -FLT_MAX, m5 = -FLT_MAX, m6 = -FLT_MAX, m7 = -FLT_MAX;
#pragma unroll
    for (int k = 0; k < KNN; ++k) {
        int row = nbr[pl][k];
        uint4 vv = *(const uint4*)(V + (size_t)row * H + c8 * 8);
        m0 = fmaxf(m0, __uint_as_float(vv.x << 16));
        m1 = fmaxf(m1, __uint_as_float(vv.x & 0xFFFF0000u));
        m2 = fmaxf(m2, __uint_as_float(vv.y << 16));
        m3 = fmaxf(m3, __uint_as_float(vv.y & 0xFFFF0000u));
        m4 = fmaxf(m4, __uint_as_float(vv.z << 16));
        m5 = fmaxf(m5, __uint_as_float(vv.z & 0xFFFF0000u));
        m6 = fmaxf(m6, __uint_as_float(vv.w << 16));
        m7 = fmaxf(m7, __uint_as_float(vv.w & 0xFFFF0000u));
    }

    float4 oa, ob;
    oa.x = fmaxf(__uint_as_float(uu.x << 16)         + m0, 0.0f) + __uint_as_float(ss.x << 16);
    oa.y = fmaxf(__uint_as_float(uu.x & 0xFFFF0000u) + m1, 0.0f) + __uint_as_float(ss.x & 0xFFFF0000u);
    oa.z = fmaxf(__uint_as_float(uu.y << 16)         + m2, 0.0f) + __uint_as_float(ss.y << 16);
    oa.w = fmaxf(__uint_as_float(uu.y & 0xFFFF0000u) + m3, 0.0f) + __uint_as_float(ss.y & 0xFFFF0000u);
    ob.x = fmaxf(__uint_as_float(uu.z << 16)         + m4, 0.0f) + __uint_as_float(ss.z << 16);
    ob.y = fmaxf(__uint_as_float(uu.z & 0xFFFF0000u) + m5, 0.0f) + __uint_as_float(ss.z & 0xFFFF0000u);
    ob.z = fmaxf(__uint_as_float(uu.w << 16)         + m6, 0.0f) + __uint_as_float(ss.w << 16);
    ob.w = fmaxf(__uint_as_float(uu.w & 0xFFFF0000u) + m7, 0.0f) + __uint_as_float(ss.w & 0xFFFF0000u);
    ((float4*)(out + p * H))[c8 * 2]     = oa;
    ((float4*)(out + p * H))[c8 * 2 + 1] = ob;
}

// ---------------------------------------------------------------------------
extern "C" void kernel_launch(void* const* d_in, const int* in_sizes, int n_in,
                              void* d_out, int out_size, void* d_ws, size_t ws_size,
                              hipStream_t stream)
{
    const float* x    = (const float*)d_in[0];
    const float* pos  = (const float*)d_in[1];
    // d_in[2] = batch indices (implicit: i / P) -- unused
    const float* W_e  = (const float*)d_in[3];
    const float* b_e  = (const float*)d_in[4];
    const float* W_sc = (const float*)d_in[5];
    const float* b_sc = (const float*)d_in[6];
    float* out = (float*)d_out;

    char* ws = (char*)d_ws;
    // workspace layout (bytes)
    const size_t OFF_IDX  = 0;                          // N*K*4 = 2 MB
    const size_t OFF_U    = 2ull << 20;                 // N*H*2 = 8 MB
    const size_t OFF_V    = OFF_U + (8ull << 20);       // 8 MB
    const size_t OFF_S    = OFF_V + (8ull << 20);       // 8 MB
    const size_t OFF_WT   = OFF_S + (8ull << 20);       // 384*64*2 = 48 KB
    const size_t OFF_BIAS = OFF_WT + 49152;             // 384*4

    int*            idx  = (int*)(ws + OFF_IDX);
    unsigned short* U    = (unsigned short*)(ws + OFF_U);
    unsigned short* V    = (unsigned short*)(ws + OFF_V);
    unsigned short* S    = (unsigned short*)(ws + OFF_S);
    unsigned short* WT   = (unsigned short*)(ws + OFF_WT);
    float*          bias = (float*)(ws + OFF_BIAS);

    prep_w<<<(NCOLS * C) / 256, 256, 0, stream>>>(W_e, b_e, W_sc, b_sc, WT, bias);
    knn_gemm_kernel<<<512, 512, 0, stream>>>(pos, x, WT, bias, idx, U, V, S);
    final_kernel<<<N / 16, 256, 0, stream>>>(idx, U, V, S, out);
}